// Round 1
// baseline (1525.478 us; speedup 1.0000x reference)
//
#include <hip/hip_runtime.h>

typedef float floatx4 __attribute__((ext_vector_type(4)));

#define F8_MAX 448.0f
#define BM 128
#define BN 128
#define BK 64

// ---------------------------------------------------------------------------
// amax reduction: float4 grid-stride -> wave shuffle max -> block max ->
// atomicMax on uint bits (valid: all values are |x| >= 0).
// ---------------------------------------------------------------------------
__global__ void amax_kernel(const float* __restrict__ x, int n4,
                            unsigned* __restrict__ out) {
  const float4* __restrict__ x4 = (const float4*)x;
  float m = 0.0f;
  int stride = gridDim.x * blockDim.x;
  for (int i = blockIdx.x * blockDim.x + threadIdx.x; i < n4; i += stride) {
    float4 v = x4[i];
    m = fmaxf(m, fmaxf(fmaxf(fabsf(v.x), fabsf(v.y)),
                       fmaxf(fabsf(v.z), fabsf(v.w))));
  }
  for (int off = 32; off > 0; off >>= 1)
    m = fmaxf(m, __shfl_down(m, off, 64));
  __shared__ float wmax[4];
  int wave = threadIdx.x >> 6;
  if ((threadIdx.x & 63) == 0) wmax[wave] = m;
  __syncthreads();
  if (threadIdx.x == 0) {
    float bm = fmaxf(fmaxf(wmax[0], wmax[1]), fmaxf(wmax[2], wmax[3]));
    atomicMax(out, __float_as_uint(bm));
  }
}

// ---------------------------------------------------------------------------
// Quantize fp32 -> fp8 e4m3 (OCP), per-tensor scale = amax/448.
// Matches jnp: scale = amax/448 (fp32 div); q = clip(t*(1/scale), +-448)
// then RNE convert (v_cvt_pk_fp8_f32 is RNE; we pre-clamp so no overflow).
// 8 elements / thread -> 8 fp8 bytes stored as uint2.
// ---------------------------------------------------------------------------
__global__ void quant_kernel(const float* __restrict__ x,
                             unsigned char* __restrict__ q, int n8,
                             const unsigned* __restrict__ amax_bits) {
  float amax = __uint_as_float(*amax_bits);
  float scale = amax / F8_MAX;      // fp32 division, matches reference
  float inv = 1.0f / scale;         // matches reference's 1.0/scale
  const float4* __restrict__ x4 = (const float4*)x;
  uint2* __restrict__ q8 = (uint2*)q;
  int stride = gridDim.x * blockDim.x;
  for (int i = blockIdx.x * blockDim.x + threadIdx.x; i < n8; i += stride) {
    float4 a = x4[2 * i];
    float4 b = x4[2 * i + 1];
    float c0 = fminf(fmaxf(a.x * inv, -F8_MAX), F8_MAX);
    float c1 = fminf(fmaxf(a.y * inv, -F8_MAX), F8_MAX);
    float c2 = fminf(fmaxf(a.z * inv, -F8_MAX), F8_MAX);
    float c3 = fminf(fmaxf(a.w * inv, -F8_MAX), F8_MAX);
    float c4 = fminf(fmaxf(b.x * inv, -F8_MAX), F8_MAX);
    float c5 = fminf(fmaxf(b.y * inv, -F8_MAX), F8_MAX);
    float c6 = fminf(fmaxf(b.z * inv, -F8_MAX), F8_MAX);
    float c7 = fminf(fmaxf(b.w * inv, -F8_MAX), F8_MAX);
    int lo = __builtin_amdgcn_cvt_pk_fp8_f32(c0, c1, 0, false);
    lo = __builtin_amdgcn_cvt_pk_fp8_f32(c2, c3, lo, true);
    int hi = __builtin_amdgcn_cvt_pk_fp8_f32(c4, c5, 0, false);
    hi = __builtin_amdgcn_cvt_pk_fp8_f32(c6, c7, hi, true);
    uint2 r;
    r.x = (unsigned)lo;
    r.y = (unsigned)hi;
    q8[i] = r;
  }
}

// ---------------------------------------------------------------------------
// Async global->LDS, 16B per lane. LDS dest is wave-uniform base + lane*16.
// ---------------------------------------------------------------------------
__device__ inline void async_copy16(const unsigned char* g, unsigned char* l) {
  __builtin_amdgcn_global_load_lds(
      (const __attribute__((address_space(1))) void*)g,
      (__attribute__((address_space(3))) void*)l, 16, 0, 0);
}

// ---------------------------------------------------------------------------
// FP8 GEMM: C[m][n] = (sum_k Xq[m][k]*Wq[n][k]) * (sx*sw) + bias[n]
// 128x128 tile, BK=64, 4 waves (2x2), each wave 64x64 via 4x4 grid of
// 16x16x32 fp8 MFMAs. Both A (M-major) and B (N-major) are K-contiguous,
// so both fragments are 8-byte contiguous LDS reads.
// ---------------------------------------------------------------------------
__global__ void __launch_bounds__(256) gemm_fp8(
    const unsigned char* __restrict__ Xq, const unsigned char* __restrict__ Wq,
    const float* __restrict__ bias, const unsigned* __restrict__ scales,
    float* __restrict__ C, int M, int N, int K) {
  __shared__ __align__(16) unsigned char As[BM * BK];  // 8 KiB, unpadded
  __shared__ __align__(16) unsigned char Bs[BN * BK];  // 8 KiB, unpadded

  const int tid = threadIdx.x;
  const int wave = tid >> 6;
  const int lane = tid & 63;
  const int quad = lane >> 4;
  const int l16 = lane & 15;
  const int wm = wave & 1;   // wave's 64-row slab
  const int wn = wave >> 1;  // wave's 64-col slab

  const int baseM = blockIdx.y * BM;
  const int baseN = blockIdx.x * BN;

  floatx4 acc[4][4];
#pragma unroll
  for (int i = 0; i < 4; i++)
#pragma unroll
    for (int j = 0; j < 4; j++) acc[i][j] = {0.f, 0.f, 0.f, 0.f};

  // Staging: 256 threads x 16B = 4096B per instr = 64 rows of 64B.
  // Thread t -> row t/4, byte offset (t%4)*16. LDS linear offset = t*16,
  // which is exactly wave_base(w*1024) + lane*16. Two instrs per matrix.
  const int srow = tid >> 2;
  const int skoff = (tid & 3) * 16;
  const unsigned char* gA0 = Xq + (size_t)(baseM + srow) * K + skoff;
  const unsigned char* gA1 = gA0 + (size_t)64 * K;
  const unsigned char* gB0 = Wq + (size_t)(baseN + srow) * K + skoff;
  const unsigned char* gB1 = gB0 + (size_t)64 * K;
  unsigned char* lA0 = As + wave * 1024;         // wave-uniform
  unsigned char* lA1 = As + 4096 + wave * 1024;  // wave-uniform
  unsigned char* lB0 = Bs + wave * 1024;
  unsigned char* lB1 = Bs + 4096 + wave * 1024;

  // Fragment read offsets: A[m=l16][k=quad*8+j] / B[k=quad*8+j][n=l16]
  const int aRowOff = (wm * 64 + l16) * BK + quad * 8;
  const int bRowOff = (wn * 64 + l16) * BK + quad * 8;

  for (int kt = 0; kt < K; kt += BK) {
    // prev iteration's trailing __syncthreads guarantees LDS is free
    async_copy16(gA0 + kt, lA0);
    async_copy16(gA1 + kt, lA1);
    async_copy16(gB0 + kt, lB0);
    async_copy16(gB1 + kt, lB1);
    __syncthreads();  // drains vmcnt(0): tiles resident
#pragma unroll
    for (int ks = 0; ks < 2; ks++) {
      long a[4], b[4];
#pragma unroll
      for (int i = 0; i < 4; i++)
        a[i] = *(const long*)(As + aRowOff + i * 16 * BK + ks * 32);
#pragma unroll
      for (int i = 0; i < 4; i++)
        b[i] = *(const long*)(Bs + bRowOff + i * 16 * BK + ks * 32);
#pragma unroll
      for (int mi = 0; mi < 4; mi++)
#pragma unroll
        for (int ni = 0; ni < 4; ni++)
          acc[mi][ni] = __builtin_amdgcn_mfma_f32_16x16x32_fp8_fp8(
              a[mi], b[ni], acc[mi][ni], 0, 0, 0);
    }
    __syncthreads();  // all waves done reading before next overwrite
  }

  // Epilogue: out = acc * (sx*sw) + bias[n].
  // C/D layout: col = lane&15, row = quad*4 + reg  [m89/m91 verified]
  const float s = (__uint_as_float(scales[0]) / F8_MAX) *
                  (__uint_as_float(scales[1]) / F8_MAX);
#pragma unroll
  for (int ni = 0; ni < 4; ni++) {
    const int gn = baseN + wn * 64 + ni * 16 + l16;
    const float bv = bias[gn];
#pragma unroll
    for (int mi = 0; mi < 4; mi++) {
      const int gm = baseM + wm * 64 + mi * 16 + quad * 4;
      float* outp = C + (size_t)gm * N + gn;
#pragma unroll
      for (int r = 0; r < 4; r++) outp[(size_t)r * N] = acc[mi][ni][r] * s + bv;
    }
  }
}

// ---------------------------------------------------------------------------
// Launcher. Workspace layout:
//   ws[0..3]   : uint amax_x bits
//   ws[4..7]   : uint amax_w bits
//   ws+256    : Xq (M*K fp8)
//   ws+256+MK : Wq (N*K fp8)
// ---------------------------------------------------------------------------
extern "C" void kernel_launch(void* const* d_in, const int* in_sizes, int n_in,
                              void* d_out, int out_size, void* d_ws,
                              size_t ws_size, hipStream_t stream) {
  const float* x = (const float*)d_in[0];
  const float* w = (const float*)d_in[1];
  const float* bias = (const float*)d_in[2];
  float* out = (float*)d_out;

  const int N = in_sizes[2];           // 4096
  const int K = in_sizes[1] / N;       // 4096
  const int M = in_sizes[0] / K;       // 16384

  unsigned* scales = (unsigned*)d_ws;
  unsigned char* xq = (unsigned char*)d_ws + 256;
  unsigned char* wq = xq + (size_t)M * K;

  hipMemsetAsync(d_ws, 0, 256, stream);  // ws is re-poisoned every launch
  amax_kernel<<<2048, 256, 0, stream>>>(x, (M * K) / 4, scales + 0);
  amax_kernel<<<1024, 256, 0, stream>>>(w, (N * K) / 4, scales + 1);
  quant_kernel<<<2048, 256, 0, stream>>>(x, xq, (M * K) / 8, scales + 0);
  quant_kernel<<<1024, 256, 0, stream>>>(w, wq, (N * K) / 8, scales + 1);

  dim3 grid(N / BN, M / BM);
  gemm_fp8<<<grid, 256, 0, stream>>>(xq, wq, bias, scales, out, M, N, K);
}

// Round 2
// 1041.611 us; speedup vs baseline: 1.4645x; 1.4645x over previous
//
#include <hip/hip_runtime.h>

typedef float floatx4 __attribute__((ext_vector_type(4)));
typedef long longx2 __attribute__((ext_vector_type(2)));

#define F8_MAX 448.0f
#define BM 128
#define BN 128
#define BK 64

// ---------------------------------------------------------------------------
// amax reduction: float4 grid-stride -> wave shuffle max -> block max ->
// atomicMax on uint bits (valid: all values are |x| >= 0).
// ---------------------------------------------------------------------------
__global__ void amax_kernel(const float* __restrict__ x, int n4,
                            unsigned* __restrict__ out) {
  const float4* __restrict__ x4 = (const float4*)x;
  float m = 0.0f;
  int stride = gridDim.x * blockDim.x;
  for (int i = blockIdx.x * blockDim.x + threadIdx.x; i < n4; i += stride) {
    float4 v = x4[i];
    m = fmaxf(m, fmaxf(fmaxf(fabsf(v.x), fabsf(v.y)),
                       fmaxf(fabsf(v.z), fabsf(v.w))));
  }
  for (int off = 32; off > 0; off >>= 1)
    m = fmaxf(m, __shfl_down(m, off, 64));
  __shared__ float wmax[4];
  int wave = threadIdx.x >> 6;
  if ((threadIdx.x & 63) == 0) wmax[wave] = m;
  __syncthreads();
  if (threadIdx.x == 0) {
    float bm = fmaxf(fmaxf(wmax[0], wmax[1]), fmaxf(wmax[2], wmax[3]));
    atomicMax(out, __float_as_uint(bm));
  }
}

// ---------------------------------------------------------------------------
// Quantize fp32 -> fp8 e4m3 (OCP), per-tensor scale = amax/448.
// Matches jnp: scale = amax/448 (fp32 div); q = clip(t*(1/scale), +-448)
// then RNE convert (v_cvt_pk_fp8_f32 is RNE; we pre-clamp so no overflow).
// ---------------------------------------------------------------------------
__global__ void quant_kernel(const float* __restrict__ x,
                             unsigned char* __restrict__ q, int n8,
                             const unsigned* __restrict__ amax_bits) {
  float amax = __uint_as_float(*amax_bits);
  float scale = amax / F8_MAX;      // fp32 division, matches reference
  float inv = 1.0f / scale;         // matches reference's 1.0/scale
  const float4* __restrict__ x4 = (const float4*)x;
  uint2* __restrict__ q8 = (uint2*)q;
  int stride = gridDim.x * blockDim.x;
  for (int i = blockIdx.x * blockDim.x + threadIdx.x; i < n8; i += stride) {
    float4 a = x4[2 * i];
    float4 b = x4[2 * i + 1];
    float c0 = fminf(fmaxf(a.x * inv, -F8_MAX), F8_MAX);
    float c1 = fminf(fmaxf(a.y * inv, -F8_MAX), F8_MAX);
    float c2 = fminf(fmaxf(a.z * inv, -F8_MAX), F8_MAX);
    float c3 = fminf(fmaxf(a.w * inv, -F8_MAX), F8_MAX);
    float c4 = fminf(fmaxf(b.x * inv, -F8_MAX), F8_MAX);
    float c5 = fminf(fmaxf(b.y * inv, -F8_MAX), F8_MAX);
    float c6 = fminf(fmaxf(b.z * inv, -F8_MAX), F8_MAX);
    float c7 = fminf(fmaxf(b.w * inv, -F8_MAX), F8_MAX);
    int lo = __builtin_amdgcn_cvt_pk_fp8_f32(c0, c1, 0, false);
    lo = __builtin_amdgcn_cvt_pk_fp8_f32(c2, c3, lo, true);
    int hi = __builtin_amdgcn_cvt_pk_fp8_f32(c4, c5, 0, false);
    hi = __builtin_amdgcn_cvt_pk_fp8_f32(c6, c7, hi, true);
    uint2 r;
    r.x = (unsigned)lo;
    r.y = (unsigned)hi;
    q8[i] = r;
  }
}

// ---------------------------------------------------------------------------
// Async global->LDS, 16B per lane. LDS dest is wave-uniform base + lane*16.
// ---------------------------------------------------------------------------
__device__ inline void async_copy16(const unsigned char* g, unsigned char* l) {
  __builtin_amdgcn_global_load_lds(
      (const __attribute__((address_space(1))) void*)g,
      (__attribute__((address_space(3))) void*)l, 16, 0, 0);
}

// ---------------------------------------------------------------------------
// FP8 GEMM: C[m][n] = (sum_k Xq[m][k]*Wq[n][k]) * (sx*sw) + bias[n]
// 128x128 tile, BK=64, 4 waves (2x2), each wave 64x64 via 4x4 grid of
// 16x16x32 fp8 MFMAs.
//
// LDS swizzle [R2]: row r's 16B slot s holds global chunk s^(r&3). Staging
// implements this by permuting each lane's GLOBAL source (LDS dest must stay
// lane*16 -- global_load_lds wave-uniform-base constraint). Fragment reads
// become ds_read_b128 at slot quad^(l16&3): bank base 16*(l16&1) +
// 4*(quad^(l16&3)) covers all 32 banks exactly 8x/wave = b128 minimum
// (round-1 b64 pattern was 8-way on 16 banks -> 4.7e8 conflict cycles).
//
// k-permutation [R2]: each lane's 16B chunk feeds 2 MFMAs (low 8B -> first,
// high 8B -> second). This reorders the k-reduction identically for A and B
// (both fragments use layout [idx=l16][k=quad*8+j]), so the products still
// pair correctly -- sum over k is order-free.
// ---------------------------------------------------------------------------
__global__ void __launch_bounds__(256) gemm_fp8(
    const unsigned char* __restrict__ Xq, const unsigned char* __restrict__ Wq,
    const float* __restrict__ bias, const unsigned* __restrict__ scales,
    float* __restrict__ C, int M, int N, int K) {
  __shared__ __align__(16) unsigned char As[BM * BK];  // 8 KiB
  __shared__ __align__(16) unsigned char Bs[BN * BK];  // 8 KiB

  const int tid = threadIdx.x;
  const int wave = tid >> 6;
  const int lane = tid & 63;
  const int quad = lane >> 4;
  const int l16 = lane & 15;
  const int wm = wave & 1;   // wave's 64-row slab
  const int wn = wave >> 1;  // wave's 64-col slab

  const int baseM = blockIdx.y * BM;
  const int baseN = blockIdx.x * BN;

  floatx4 acc[4][4];
#pragma unroll
  for (int i = 0; i < 4; i++)
#pragma unroll
    for (int j = 0; j < 4; j++) acc[i][j] = {0.f, 0.f, 0.f, 0.f};

  // Staging: 256 threads x 16B = 4096B = 64 rows x 64B. Thread t covers
  // row t>>2, LDS slot t&3; its GLOBAL chunk is swizzled: (t&3)^(row&3).
  const int srow = tid >> 2;
  const int skoff = ((tid & 3) ^ (srow & 3)) * 16;  // swizzled global chunk
  const unsigned char* gA0 = Xq + (size_t)(baseM + srow) * K + skoff;
  const unsigned char* gA1 = gA0 + (size_t)64 * K;
  const unsigned char* gB0 = Wq + (size_t)(baseN + srow) * K + skoff;
  const unsigned char* gB1 = gB0 + (size_t)64 * K;
  unsigned char* lA0 = As + wave * 1024;         // wave-uniform
  unsigned char* lA1 = As + 4096 + wave * 1024;  // wave-uniform
  unsigned char* lB0 = Bs + wave * 1024;
  unsigned char* lB1 = Bs + 4096 + wave * 1024;

  // Fragment b128 read offsets: row (wm*64 + mi*16 + l16), slot quad^(l16&3).
  // (mi*16 and wm*64 are 0 mod 4, so row&3 == l16&3.)
  const int aOff = (wm * 64 + l16) * BK + ((quad ^ (l16 & 3)) * 16);
  const int bOff = (wn * 64 + l16) * BK + ((quad ^ (l16 & 3)) * 16);

  for (int kt = 0; kt < K; kt += BK) {
    // prev iteration's trailing __syncthreads guarantees LDS is free
    async_copy16(gA0 + kt, lA0);
    async_copy16(gA1 + kt, lA1);
    async_copy16(gB0 + kt, lB0);
    async_copy16(gB1 + kt, lB1);
    __syncthreads();  // drains vmcnt(0): tiles resident

    longx2 a[4], b[4];
#pragma unroll
    for (int i = 0; i < 4; i++)
      a[i] = *(const longx2*)(As + aOff + i * 16 * BK);
#pragma unroll
    for (int i = 0; i < 4; i++)
      b[i] = *(const longx2*)(Bs + bOff + i * 16 * BK);
#pragma unroll
    for (int mi = 0; mi < 4; mi++)
#pragma unroll
      for (int ni = 0; ni < 4; ni++)
        acc[mi][ni] = __builtin_amdgcn_mfma_f32_16x16x32_fp8_fp8(
            a[mi].x, b[ni].x, acc[mi][ni], 0, 0, 0);
#pragma unroll
    for (int mi = 0; mi < 4; mi++)
#pragma unroll
      for (int ni = 0; ni < 4; ni++)
        acc[mi][ni] = __builtin_amdgcn_mfma_f32_16x16x32_fp8_fp8(
            a[mi].y, b[ni].y, acc[mi][ni], 0, 0, 0);

    __syncthreads();  // all waves done reading before next overwrite
  }

  // Epilogue: out = acc * (sx*sw) + bias[n].
  // C/D layout: col = lane&15, row = quad*4 + reg  [m89/m91 verified]
  const float s = (__uint_as_float(scales[0]) / F8_MAX) *
                  (__uint_as_float(scales[1]) / F8_MAX);
#pragma unroll
  for (int ni = 0; ni < 4; ni++) {
    const int gn = baseN + wn * 64 + ni * 16 + l16;
    const float bv = bias[gn];
#pragma unroll
    for (int mi = 0; mi < 4; mi++) {
      const int gm = baseM + wm * 64 + mi * 16 + quad * 4;
      float* outp = C + (size_t)gm * N + gn;
#pragma unroll
      for (int r = 0; r < 4; r++) outp[(size_t)r * N] = acc[mi][ni][r] * s + bv;
    }
  }
}

// ---------------------------------------------------------------------------
// Launcher. Workspace layout:
//   ws[0..3]   : uint amax_x bits
//   ws[4..7]   : uint amax_w bits
//   ws+256    : Xq (M*K fp8)
//   ws+256+MK : Wq (N*K fp8)
// ---------------------------------------------------------------------------
extern "C" void kernel_launch(void* const* d_in, const int* in_sizes, int n_in,
                              void* d_out, int out_size, void* d_ws,
                              size_t ws_size, hipStream_t stream) {
  const float* x = (const float*)d_in[0];
  const float* w = (const float*)d_in[1];
  const float* bias = (const float*)d_in[2];
  float* out = (float*)d_out;

  const int N = in_sizes[2];           // 4096
  const int K = in_sizes[1] / N;       // 4096
  const int M = in_sizes[0] / K;       // 16384

  unsigned* scales = (unsigned*)d_ws;
  unsigned char* xq = (unsigned char*)d_ws + 256;
  unsigned char* wq = xq + (size_t)M * K;

  hipMemsetAsync(d_ws, 0, 256, stream);  // ws is re-poisoned every launch
  amax_kernel<<<4096, 256, 0, stream>>>(x, (M * K) / 4, scales + 0);
  amax_kernel<<<1024, 256, 0, stream>>>(w, (N * K) / 4, scales + 1);
  quant_kernel<<<4096, 256, 0, stream>>>(x, xq, (M * K) / 8, scales + 0);
  quant_kernel<<<1024, 256, 0, stream>>>(w, wq, (N * K) / 8, scales + 1);

  dim3 grid(N / BN, M / BM);
  gemm_fp8<<<grid, 256, 0, stream>>>(xq, wq, bias, scales, out, M, N, K);
}